// Round 1
// 629.383 us; speedup vs baseline: 1.0216x; 1.0216x over previous
//
#include <hip/hip_runtime.h>

// Problem constants (from reference):
//   B=32, T=2048, D=1536, AUDIO_DIM=1280, V=256, NT=2, NF=2, TR=0.2, FR=0.15
#define AUDIO_DIM_ 1280
#define B_ 32
#define T_ 2048
#define D_ 1536
#define V_ (D_ - AUDIO_DIM_)   // 256
#define ND4_ (D_ / 4)          // 384 float4 per row
#define NV4_ (V_ / 4)          // 64 float4 video prefix
#define ROWS_ 8                // rows (t values) per block

// Native vector type so __builtin_nontemporal_{load,store} apply directly.
typedef float f4 __attribute__((ext_vector_type(4)));

__device__ __forceinline__ bool in_iv(int v, int lo, int hi) {
    return (v >= lo) && (v < hi);
}

// ---------------------------------------------------------------------------
// Single fused kernel.
//  grid  = (T/ROWS_, B), block = 384 threads (6 waves).
//  threadIdx.x == d4 (float4 column). Wave 0 (lanes 0..63) is exactly the
//  256-ch video prefix -> the isV branch is wave-uniform, zero divergence.
//  The time-mask is block-uniform -> scalar branch; masked rows skip the
//  audio read entirely (zeros written).
//  Mask bounds are recomputed redundantly per thread from uniform addresses
//  (compiler scalarizes to s_loads); float arithmetic replicates reference:
//   max_t = floor(len*0.2); t = floor(u_t*(max_t+1))
//   rem = len-t; t0 = rem<=0 ? 0 : floor(u_t0*(rem+1))
//   f = floor(u_f*193); f0max = clip(1280-f,0); f0 = floor(u_f0*(f0max+1))
//  Audio output = Aud * keep (same multiply as reference -> bit-exact).
// ---------------------------------------------------------------------------
__global__ __launch_bounds__(384) void specaug_kernel(
    const f4* __restrict__ X, f4* __restrict__ out,
    const int*   __restrict__ lengths,
    const float* __restrict__ u_t,  const float* __restrict__ u_t0,
    const float* __restrict__ u_f,  const float* __restrict__ u_f0)
{
    const int b   = blockIdx.y;
    const int tb0 = blockIdx.x * ROWS_;
    const int tid = threadIdx.x;          // d4 column, 0..383

    // --- per-batch time-mask bounds (uniform, scalar-cached) ---
    const int   len   = lengths[b];
    const float max_t = floorf((float)len * 0.2f);

    int t0a, tea, t0b, teb;
    {
        int t   = (int)floorf(u_t[b] * (max_t + 1.0f));
        int rem = len - t;
        int t0  = (rem <= 0) ? 0 : (int)floorf(u_t0[b] * ((float)rem + 1.0f));
        t0a = t0; tea = t0 + t;

        t   = (int)floorf(u_t[B_ + b] * (max_t + 1.0f));
        rem = len - t;
        t0  = (rem <= 0) ? 0 : (int)floorf(u_t0[B_ + b] * ((float)rem + 1.0f));
        t0b = t0; teb = t0 + t;
    }

    // --- per-batch freq-mask bounds ---
    int f0a, fea, f0b, feb;
    {
        int f     = (int)floorf(u_f[b] * 193.0f);            // max_f = 192
        int f0max = AUDIO_DIM_ - f; if (f0max < 0) f0max = 0;
        int f0    = (int)floorf(u_f0[b] * ((float)f0max + 1.0f));
        f0a = f0; fea = f0 + f;

        f     = (int)floorf(u_f[B_ + b] * 193.0f);
        f0max = AUDIO_DIM_ - f; if (f0max < 0) f0max = 0;
        f0    = (int)floorf(u_f0[B_ + b] * ((float)f0max + 1.0f));
        f0b = f0; feb = f0 + f;
    }

    // --- per-thread channel keep-multiplier (computed once) ---
    const bool isV = (tid < NV4_);        // wave 0 exactly
    float m0 = 1.f, m1 = 1.f, m2 = 1.f, m3 = 1.f;
    if (!isV) {
        const int ff = (tid - NV4_) * 4;  // audio channel of component .x
        m0 = (in_iv(ff + 0, f0a, fea) || in_iv(ff + 0, f0b, feb)) ? 0.f : 1.f;
        m1 = (in_iv(ff + 1, f0a, fea) || in_iv(ff + 1, f0b, feb)) ? 0.f : 1.f;
        m2 = (in_iv(ff + 2, f0a, fea) || in_iv(ff + 2, f0b, feb)) ? 0.f : 1.f;
        m3 = (in_iv(ff + 3, f0a, fea) || in_iv(ff + 3, f0b, feb)) ? 0.f : 1.f;
    }
    const f4 m = {m0, m1, m2, m3};

    // --- streaming copy: 8 rows, one float4 per row per thread ---
    const int base = (b * T_ + tb0) * ND4_ + tid;
    #pragma unroll
    for (int r = 0; r < ROWS_; ++r) {
        const int  t   = tb0 + r;
        const bool tm  = in_iv(t, t0a, tea) || in_iv(t, t0b, teb); // block-uniform
        const int  idx = base + r * ND4_;

        f4 x = {0.f, 0.f, 0.f, 0.f};
        if (isV) {
            x = __builtin_nontemporal_load(X + idx);       // video: verbatim copy
        } else if (!tm) {
            x = __builtin_nontemporal_load(X + idx) * m;   // audio: Aud * keep
        }                                                  // tm row: skip read, write 0
        __builtin_nontemporal_store(x, out + idx);
    }
}

extern "C" void kernel_launch(void* const* d_in, const int* in_sizes, int n_in,
                              void* d_out, int out_size, void* d_ws, size_t ws_size,
                              hipStream_t stream) {
    const f4*    X       = (const f4*)   d_in[0];
    const int*   lengths = (const int*)  d_in[1];
    const float* u_t     = (const float*)d_in[2];
    const float* u_t0    = (const float*)d_in[3];
    const float* u_f     = (const float*)d_in[4];
    const float* u_f0    = (const float*)d_in[5];
    f4*          out     = (f4*)d_out;

    dim3 grid(T_ / ROWS_, B_);            // (256, 32) = 8192 blocks
    specaug_kernel<<<grid, 384, 0, stream>>>(X, out, lengths,
                                             u_t, u_t0, u_f, u_f0);
}